// Round 1
// baseline (607.808 us; speedup 1.0000x reference)
//
#include <hip/hip_runtime.h>

// 2-layer GCN + mean pool.
// ws layout (floats, n = N_NODES):
//   deg  : [0,      n)
//   dinv : [n,     2n)
//   g1   : [2n,   18n)   n x 16
//   acc1 : [18n,  34n)   n x 16
//   g2   : [34n,  66n)   n x 32
//   acc2 : [66n,  98n)   n x 32

__global__ void init_kernel(float* __restrict__ deg, float* __restrict__ out,
                            const float* __restrict__ b2, int n) {
    int i = blockIdx.x * blockDim.x + threadIdx.x;
    if (i < n) deg[i] = 1.0f;          // self-loop contribution
    if (i < 32) out[i] = b2[i];        // bias folded into pooled output
}

__global__ void deg_kernel(const int* __restrict__ dst, float* __restrict__ deg, int E) {
    int e = blockIdx.x * blockDim.x + threadIdx.x;
    if (e < E) atomicAdd(&deg[dst[e]], 1.0f);
}

// h1 = x @ W1 ; g1 = h1 * dinv ; acc1 = g1 (self-loop pre-added)
__global__ void node1_kernel(const float* __restrict__ x, const float* __restrict__ W1,
                             const float* __restrict__ deg, float* __restrict__ dinv,
                             float* __restrict__ g1, float* __restrict__ acc1, int n) {
    int t = blockIdx.x * blockDim.x + threadIdx.x;
    int i = t >> 4, k = t & 15;
    if (i >= n) return;
    float di = rsqrtf(deg[i]);
    if (k == 0) dinv[i] = di;
    float h = x[i * 3 + 0] * W1[0 * 16 + k]
            + x[i * 3 + 1] * W1[1 * 16 + k]
            + x[i * 3 + 2] * W1[2 * 16 + k];
    float g = h * di;
    g1[i * 16 + k] = g;
    acc1[i * 16 + k] = g;
}

__global__ void scatter16_kernel(const float* __restrict__ g, float* __restrict__ acc,
                                 const int* __restrict__ src, const int* __restrict__ dst, int E) {
    int t = blockIdx.x * blockDim.x + threadIdx.x;
    int e = t >> 4, k = t & 15;
    if (e >= E) return;
    atomicAdd(&acc[dst[e] * 16 + k], g[src[e] * 16 + k]);
}

// h = relu(dinv*acc1 + b1) ; g2 = (h @ W2) * dinv ; acc2 = g2
__global__ void node2_kernel(const float* __restrict__ acc1, const float* __restrict__ dinv,
                             const float* __restrict__ b1, const float* __restrict__ W2,
                             float* __restrict__ g2, float* __restrict__ acc2, int n) {
    int t = blockIdx.x * blockDim.x + threadIdx.x;
    int i = t >> 5, j = t & 31;
    if (i >= n) return;
    float di = dinv[i];
    float s = 0.0f;
#pragma unroll
    for (int k = 0; k < 16; ++k) {
        float h = di * acc1[i * 16 + k] + b1[k];
        h = fmaxf(h, 0.0f);
        s += h * W2[k * 32 + j];
    }
    float g = s * di;
    g2[i * 32 + j] = g;
    acc2[i * 32 + j] = g;
}

__global__ void scatter32_kernel(const float* __restrict__ g, float* __restrict__ acc,
                                 const int* __restrict__ src, const int* __restrict__ dst, int E) {
    int t = blockIdx.x * blockDim.x + threadIdx.x;
    int e = t >> 5, k = t & 31;
    if (e >= E) return;
    atomicAdd(&acc[dst[e] * 32 + k], g[src[e] * 32 + k]);
}

// out[j] += mean_i( dinv[i] * acc2[i][j] )
__global__ void reduce_kernel(const float* __restrict__ acc2, const float* __restrict__ dinv,
                              float* __restrict__ out, int n, float invN) {
    __shared__ float smem[32];
    int tid = threadIdx.x;
    if (tid < 32) smem[tid] = 0.0f;
    __syncthreads();
    int f = tid & 31;
    int g = (blockIdx.x * blockDim.x + tid) >> 5;
    int G = (gridDim.x * blockDim.x) >> 5;
    float sum = 0.0f;
    for (int i = g; i < n; i += G) sum += acc2[i * 32 + f] * dinv[i];
    atomicAdd(&smem[f], sum);
    __syncthreads();
    if (tid < 32) atomicAdd(&out[tid], smem[tid] * invN);
}

extern "C" void kernel_launch(void* const* d_in, const int* in_sizes, int n_in,
                              void* d_out, int out_size, void* d_ws, size_t ws_size,
                              hipStream_t stream) {
    const float* x   = (const float*)d_in[0];
    const int*   ei  = (const int*)d_in[1];   // [2, E] int32 (JAX x64 disabled)
    const float* W1  = (const float*)d_in[2];
    const float* b1  = (const float*)d_in[3];
    const float* W2  = (const float*)d_in[4];
    const float* b2  = (const float*)d_in[5];
    float* out = (float*)d_out;

    const int n = in_sizes[0] / 3;
    const int E = in_sizes[1] / 2;
    const int* src = ei;
    const int* dst = ei + E;

    float* ws   = (float*)d_ws;
    float* deg  = ws;
    float* dinv = ws + (size_t)n;
    float* g1   = ws + (size_t)2 * n;
    float* acc1 = ws + (size_t)18 * n;
    float* g2   = ws + (size_t)34 * n;
    float* acc2 = ws + (size_t)66 * n;

    const int B = 256;
    init_kernel<<<(n + B - 1) / B, B, 0, stream>>>(deg, out, b2, n);
    deg_kernel<<<(E + B - 1) / B, B, 0, stream>>>(dst, deg, E);
    node1_kernel<<<((size_t)n * 16 + B - 1) / B, B, 0, stream>>>(x, W1, deg, dinv, g1, acc1, n);
    scatter16_kernel<<<((size_t)E * 16 + B - 1) / B, B, 0, stream>>>(g1, acc1, src, dst, E);
    node2_kernel<<<((size_t)n * 32 + B - 1) / B, B, 0, stream>>>(acc1, dinv, b1, W2, g2, acc2, n);
    scatter32_kernel<<<((size_t)E * 32 + B - 1) / B, B, 0, stream>>>(g2, acc2, src, dst, E);
    reduce_kernel<<<256, B, 0, stream>>>(acc2, dinv, out, n, 1.0f / (float)n);
}